// Round 1
// baseline (282.290 us; speedup 1.0000x reference)
//
#include <hip/hip_runtime.h>
#include <math.h>

// Problem: B=32, T=512, F=64, O=64.
// delta[b,t,f] = (t==0) ? 0 : in[b,t,f]-in[b,t-1,f]
// x = (delta - bn_mean) * (bn_w * rsqrt(bn_var+1e-5)) + bn_b
// enc_o = x * enc_w[o] + enc_b[o]
// LIF scan over o: h = v + (enc_o - v)/2 ; s = (h>=1) ; v = s?0:h
// out[b,o,f,t] = s   (fp32, 0/1)
//
// R4: XCD-aware swizzle. Block->XCD assignment is round-robin (bid%8), so
// without swizzle each XCD's private L2 collects dirty lines from 128
// address-scattered 4KB islands per o-step and drains them unsorted to
// HBM. Swizzle vbid = (bid&7)*128 + (bid>>3) gives each XCD a CONTIGUOUS
// bf-range -> per o-step its L2 holds a few large contiguous dirty runs
// (full 128KB [F,T] slabs per b) -> sequential DRAM-row drain.
// Also: no LDS — enc_w[o]/enc_b[o] are wave-uniform loads (s_load), and
// VGPR count stays ~20 for max occupancy.
//
// R5 (this round): NONTEMPORAL stores. Decomposition of dur_us shows the
// kernel portion runs at ~2.5 TB/s effective write BW while the harness's
// own fillBuffer hits 6.6 TB/s on the same surface. Output lines are
// write-once, never re-read, fully covered (1KB contiguous per wave
// store) — the exact case where L2 write-allocate + LRU dirty-eviction
// only adds disorder to the HBM drain. R4's swizzle win proved drain
// order is the sensitive resource; __builtin_nontemporal_store (emits
// global_store_dwordx4 ... nt) streams lines past the dirty-line
// machinery in address order.

#define B_DIM 32
#define T_DIM 512
#define F_DIM 64
#define O_DIM 64

typedef float v4f __attribute__((ext_vector_type(4)));

__global__ __launch_bounds__(256) void delta_lif_kernel(
    const float* __restrict__ in,     // [B,T,F]
    const float* __restrict__ enc_w,  // [64] (O,1)
    const float* __restrict__ enc_b,  // [64]
    const float* __restrict__ bn_w,   // [1]
    const float* __restrict__ bn_b,   // [1]
    const float* __restrict__ bn_mean,// [1]
    const float* __restrict__ bn_var, // [1]
    float* __restrict__ out)          // [B,O,F,T]
{
#pragma clang fp contract(off)
    // BatchNorm scalars — replicate reference op order exactly.
    const float vpe  = bn_var[0] + 1e-5f;
    const float r    = (float)(1.0 / sqrt((double)vpe));
    const float inv  = bn_w[0] * r;
    const float mean = bn_mean[0];
    const float bnb  = bn_b[0];

    // XCD swizzle: consecutive vbid -> consecutive addresses on ONE XCD.
    const int bid  = blockIdx.x;                 // 0..1023
    const int vbid = ((bid & 7) << 7) + (bid >> 3);

    // block covers bf-pair {2*vbid, 2*vbid+1}; thread: f_idx = lt>>7,
    // t4 = lt&127. Wave = 64 consecutive t4, same f -> 1KB contiguous
    // per dwordx4 store.
    const int lt    = threadIdx.x;
    const int bf    = (vbid << 1) + (lt >> 7);
    const int t0    = (lt & 127) << 2;
    const int b     = bf >> 6;
    const int f     = bf & 63;

    // input: in[b, t, f] = in[b*T*F + t*F + f]
    const float* pin = in + b * (T_DIM * F_DIM) + f;
    const float c0 = pin[(t0 + 0) * F_DIM];
    const float c1 = pin[(t0 + 1) * F_DIM];
    const float c2 = pin[(t0 + 2) * F_DIM];
    const float c3 = pin[(t0 + 3) * F_DIM];
    const float p  = (t0 == 0) ? c0 : pin[(t0 - 1) * F_DIM];

    const float x0 = ((c0 - p)  - mean) * inv + bnb;
    const float x1 = ((c1 - c0) - mean) * inv + bnb;
    const float x2 = ((c2 - c1) - mean) * inv + bnb;
    const float x3 = ((c3 - c2) - mean) * inv + bnb;

    float v0 = 0.0f, v1 = 0.0f, v2 = 0.0f, v3 = 0.0f;

    // out[b,o,f,t] = out[(b<<21) + (o<<15) + (f<<9) + t]
    float* pout = out + (b << 21) + (f << 9) + t0;

#pragma unroll 8
    for (int o = 0; o < O_DIM; ++o) {
        // wave-uniform -> scalar loads, no LDS round-trip
        const float w  = enc_w[o];
        const float bb = enc_b[o];

        const float e0 = x0 * w + bb;
        const float e1 = x1 * w + bb;
        const float e2 = x2 * w + bb;
        const float e3 = x3 * w + bb;

        // h = v + (e - v)/2 ; /2 exact -> *0.5f identical
        const float h0 = v0 + (e0 - v0) * 0.5f;
        const float h1 = v1 + (e1 - v1) * 0.5f;
        const float h2 = v2 + (e2 - v2) * 0.5f;
        const float h3 = v3 + (e3 - v3) * 0.5f;

        const bool g0 = (h0 >= 1.0f);
        const bool g1 = (h1 >= 1.0f);
        const bool g2 = (h2 >= 1.0f);
        const bool g3 = (h3 >= 1.0f);

        v4f s;
        s.x = g0 ? 1.0f : 0.0f;
        s.y = g1 ? 1.0f : 0.0f;
        s.z = g2 ? 1.0f : 0.0f;
        s.w = g3 ? 1.0f : 0.0f;

        v0 = g0 ? 0.0f : h0;
        v1 = g1 ? 0.0f : h1;
        v2 = g2 ? 0.0f : h2;
        v3 = g3 ? 0.0f : h3;

        // R5: nontemporal streaming store (write-once, full-line-covered)
        __builtin_nontemporal_store(s, (v4f*)(pout + (o << 15)));
    }
}

extern "C" void kernel_launch(void* const* d_in, const int* in_sizes, int n_in,
                              void* d_out, int out_size, void* d_ws, size_t ws_size,
                              hipStream_t stream) {
    const float* in      = (const float*)d_in[0];
    const float* enc_w   = (const float*)d_in[1];
    const float* enc_b   = (const float*)d_in[2];
    const float* bn_w    = (const float*)d_in[3];
    const float* bn_b    = (const float*)d_in[4];
    const float* bn_mean = (const float*)d_in[5];
    const float* bn_var  = (const float*)d_in[6];
    float* out = (float*)d_out;

    // 1024 blocks (512 bf-pairs, XCD-swizzled) x 256 threads
    delta_lif_kernel<<<dim3(1024), dim3(256), 0, stream>>>(
        in, enc_w, enc_b, bn_w, bn_b, bn_mean, bn_var, out);
}

// Round 2
// 274.748 us; speedup vs baseline: 1.0275x; 1.0275x over previous
//
#include <hip/hip_runtime.h>
#include <math.h>

// Problem: B=32, T=512, F=64, O=64.
// delta[b,t,f] = (t==0) ? 0 : in[b,t,f]-in[b,t-1,f]
// x = (delta - bn_mean) * (bn_w * rsqrt(bn_var+1e-5)) + bn_b
// enc_o = x * enc_w[o] + enc_b[o]
// LIF scan over o: h = v + (enc_o - v)/2 ; s = (h>=1) ; v = s?0:h
// out[b,o,f,t] = s   (fp32, 0/1)
//
// R4: XCD-aware swizzle — each XCD owns a CONTIGUOUS 32 MiB output range
// so its private L2 drains large sequential dirty runs. (kept)
// R5: nontemporal stores — REGRESSED (+6 µs); nt gives up L2 write
// buffering without improving the HBM drain. Reverted.
// R6 (this round): o-split for full occupancy. 1024 blocks = 4 blocks/CU
// = 16/32 wave slots (50%). The scan over o serializes per (b,f,t), but
// scan steps are ~16 VALU ops — recomputing 32 silent steps costs ~1k
// cycles/wave. Split o into two halves: 2048 blocks, half 1 recomputes
// v through o=0..31 without storing, then stores o=32..63. Same fp ops
// in same order -> bitwise-identical output. 8 blocks/CU = 32 waves/CU
// (100%), 2x the in-flight store streams per CU.

#define B_DIM 32
#define T_DIM 512
#define F_DIM 64
#define O_DIM 64

typedef float v4f __attribute__((ext_vector_type(4)));

__global__ __launch_bounds__(256) void delta_lif_kernel(
    const float* __restrict__ in,     // [B,T,F]
    const float* __restrict__ enc_w,  // [64] (O,1)
    const float* __restrict__ enc_b,  // [64]
    const float* __restrict__ bn_w,   // [1]
    const float* __restrict__ bn_b,   // [1]
    const float* __restrict__ bn_mean,// [1]
    const float* __restrict__ bn_var, // [1]
    float* __restrict__ out)          // [B,O,F,T]
{
#pragma clang fp contract(off)
    // BatchNorm scalars — replicate reference op order exactly.
    const float vpe  = bn_var[0] + 1e-5f;
    const float r    = (float)(1.0 / sqrt((double)vpe));
    const float inv  = bn_w[0] * r;
    const float mean = bn_mean[0];
    const float bnb  = bn_b[0];

    // XCD swizzle: 2048 blocks, 8 XCDs x 256 consecutive vbids.
    // vbid -> (pair = vbid>>1, half = vbid&1): each XCD covers 128
    // consecutive bf-pairs (= 4 b-slabs = 32 MiB contiguous output).
    const int bid  = blockIdx.x;                 // 0..2047
    const int vbid = ((bid & 7) << 8) + (bid >> 3);
    const int pair = vbid >> 1;
    const int half = vbid & 1;                   // o-half: 0 -> 0..31, 1 -> 32..63

    // block covers bf-pair {2*pair, 2*pair+1}; thread: f_idx = lt>>7,
    // t4 = lt&127. Wave = 64 consecutive t4, same f -> 1KB contiguous
    // per dwordx4 store.
    const int lt    = threadIdx.x;
    const int bf    = (pair << 1) + (lt >> 7);
    const int t0    = (lt & 127) << 2;
    const int b     = bf >> 6;
    const int f     = bf & 63;

    // input: in[b, t, f] = in[b*T*F + t*F + f]
    const float* pin = in + b * (T_DIM * F_DIM) + f;
    const float c0 = pin[(t0 + 0) * F_DIM];
    const float c1 = pin[(t0 + 1) * F_DIM];
    const float c2 = pin[(t0 + 2) * F_DIM];
    const float c3 = pin[(t0 + 3) * F_DIM];
    const float p  = (t0 == 0) ? c0 : pin[(t0 - 1) * F_DIM];

    const float x0 = ((c0 - p)  - mean) * inv + bnb;
    const float x1 = ((c1 - c0) - mean) * inv + bnb;
    const float x2 = ((c2 - c1) - mean) * inv + bnb;
    const float x3 = ((c3 - c2) - mean) * inv + bnb;

    float v0 = 0.0f, v1 = 0.0f, v2 = 0.0f, v3 = 0.0f;

    // out[b,o,f,t] = out[(b<<21) + (o<<15) + (f<<9) + t]
    float* pout = out + (b << 21) + (f << 9) + t0;

    const int o_begin = half << 5;   // 0 or 32

    // Silent warm-up: advance scan state to o_begin (no stores).
    // Same arithmetic as the storing loop -> bitwise-identical v.
#pragma unroll 8
    for (int o = 0; o < o_begin; ++o) {
        const float w  = enc_w[o];
        const float bb = enc_b[o];
        const float h0 = v0 + ((x0 * w + bb) - v0) * 0.5f;
        const float h1 = v1 + ((x1 * w + bb) - v1) * 0.5f;
        const float h2 = v2 + ((x2 * w + bb) - v2) * 0.5f;
        const float h3 = v3 + ((x3 * w + bb) - v3) * 0.5f;
        v0 = (h0 >= 1.0f) ? 0.0f : h0;
        v1 = (h1 >= 1.0f) ? 0.0f : h1;
        v2 = (h2 >= 1.0f) ? 0.0f : h2;
        v3 = (h3 >= 1.0f) ? 0.0f : h3;
    }

#pragma unroll 8
    for (int oi = 0; oi < 32; ++oi) {
        const int o = o_begin + oi;
        // wave-uniform -> scalar loads, no LDS round-trip
        const float w  = enc_w[o];
        const float bb = enc_b[o];

        const float e0 = x0 * w + bb;
        const float e1 = x1 * w + bb;
        const float e2 = x2 * w + bb;
        const float e3 = x3 * w + bb;

        // h = v + (e - v)/2 ; /2 exact -> *0.5f identical
        const float h0 = v0 + (e0 - v0) * 0.5f;
        const float h1 = v1 + (e1 - v1) * 0.5f;
        const float h2 = v2 + (e2 - v2) * 0.5f;
        const float h3 = v3 + (e3 - v3) * 0.5f;

        const bool g0 = (h0 >= 1.0f);
        const bool g1 = (h1 >= 1.0f);
        const bool g2 = (h2 >= 1.0f);
        const bool g3 = (h3 >= 1.0f);

        v4f s;
        s.x = g0 ? 1.0f : 0.0f;
        s.y = g1 ? 1.0f : 0.0f;
        s.z = g2 ? 1.0f : 0.0f;
        s.w = g3 ? 1.0f : 0.0f;

        v0 = g0 ? 0.0f : h0;
        v1 = g1 ? 0.0f : h1;
        v2 = g2 ? 0.0f : h2;
        v3 = g3 ? 0.0f : h3;

        *(v4f*)(pout + (o << 15)) = s;
    }
}

extern "C" void kernel_launch(void* const* d_in, const int* in_sizes, int n_in,
                              void* d_out, int out_size, void* d_ws, size_t ws_size,
                              hipStream_t stream) {
    const float* in      = (const float*)d_in[0];
    const float* enc_w   = (const float*)d_in[1];
    const float* enc_b   = (const float*)d_in[2];
    const float* bn_w    = (const float*)d_in[3];
    const float* bn_b    = (const float*)d_in[4];
    const float* bn_mean = (const float*)d_in[5];
    const float* bn_var  = (const float*)d_in[6];
    float* out = (float*)d_out;

    // 2048 blocks (512 bf-pairs x 2 o-halves, XCD-swizzled) x 256 threads
    delta_lif_kernel<<<dim3(2048), dim3(256), 0, stream>>>(
        in, enc_w, enc_b, bn_w, bn_b, bn_mean, bn_var, out);
}